// Round 1
// baseline (152.956 us; speedup 1.0000x reference)
//
#include <hip/hip_runtime.h>
#include <math.h>

// Problem constants (from reference setup_inputs): B=16, N=2048 samp, M=8192 ref.
#define BB 16
#define NN 2048
#define MM 8192

#define TILE_PTS 2048          // points staged in LDS per block (24 KB)
#define TILE_F4  (TILE_PTS*3/4) // 1536 float4
#define BLK 256

__device__ __forceinline__ void dist4_update(float x, float y, float z,
                                             float4 a, float4 b, float4 c,
                                             float& m0, float& m1, float& m2, float& m3) {
    float dx, dy, dz, d2;
    dx = x - a.x; dy = y - a.y; dz = z - a.z;
    d2 = dx*dx; d2 = fmaf(dy, dy, d2); d2 = fmaf(dz, dz, d2); m0 = fminf(m0, d2);
    dx = x - a.w; dy = y - b.x; dz = z - b.y;
    d2 = dx*dx; d2 = fmaf(dy, dy, d2); d2 = fmaf(dz, dz, d2); m1 = fminf(m1, d2);
    dx = x - b.z; dy = y - b.w; dz = z - c.x;
    d2 = dx*dx; d2 = fmaf(dy, dy, d2); d2 = fmaf(dz, dz, d2); m2 = fminf(m2, d2);
    dx = x - c.y; dy = y - c.z; dz = z - c.w;
    d2 = dx*dx; d2 = fmaf(dy, dy, d2); d2 = fmaf(dz, dz, d2); m3 = fminf(m3, d2);
}

// Init ws1 (partial-min array for samp->ref direction) to +inf bits.
__global__ void init_ws(unsigned int* __restrict__ ws1) {
    int i = blockIdx.x * blockDim.x + threadIdx.x;
    if (i < BB * NN) ws1[i] = 0x7F800000u;  // +inf
}

// P1: for each (b, n) samp point, min over a chunk of M ref points.
// grid = (B, N/BLK, 4 m-chunks), block = 256.
__global__ void __launch_bounds__(BLK) p1_kernel(const float* __restrict__ ref,
                                                 const float* __restrict__ samp,
                                                 unsigned int* __restrict__ ws1) {
    __shared__ float4 lds4[TILE_F4];
    const int b = blockIdx.x;
    const int ntile = blockIdx.y;
    const int mchunk = blockIdx.z;

    // stage 2048 ref points of this chunk into LDS
    const float4* src4 = (const float4*)(ref + ((size_t)b * MM + (size_t)mchunk * TILE_PTS) * 3);
    for (int i = threadIdx.x; i < TILE_F4; i += BLK) lds4[i] = src4[i];
    __syncthreads();

    const int n = ntile * BLK + threadIdx.x;
    const float* sp = samp + ((size_t)b * NN + n) * 3;
    const float x = sp[0], y = sp[1], z = sp[2];

    float m0 = INFINITY, m1 = INFINITY, m2 = INFINITY, m3 = INFINITY;
#pragma unroll 2
    for (int g = 0; g < TILE_PTS / 4; ++g) {
        float4 a = lds4[g * 3 + 0];
        float4 bq = lds4[g * 3 + 1];
        float4 c = lds4[g * 3 + 2];
        dist4_update(x, y, z, a, bq, c, m0, m1, m2, m3);
    }
    float mn = fminf(fminf(m0, m1), fminf(m2, m3));
    atomicMin(&ws1[b * NN + n], __float_as_uint(mn));  // d2 >= 0 -> uint-ordered
}

// P2: for each (b, m) ref point, min over all N samp points (fit in one LDS tile).
// grid = (B, M/BLK), block = 256.
__global__ void __launch_bounds__(BLK) p2_kernel(const float* __restrict__ ref,
                                                 const float* __restrict__ samp,
                                                 float* __restrict__ ws2) {
    __shared__ float4 lds4[TILE_F4];
    const int b = blockIdx.x;
    const int mtile = blockIdx.y;

    const float4* src4 = (const float4*)(samp + (size_t)b * NN * 3);
    for (int i = threadIdx.x; i < TILE_F4; i += BLK) lds4[i] = src4[i];
    __syncthreads();

    const int m = mtile * BLK + threadIdx.x;
    const float* rp = ref + ((size_t)b * MM + m) * 3;
    const float x = rp[0], y = rp[1], z = rp[2];

    float m0 = INFINITY, m1 = INFINITY, m2 = INFINITY, m3 = INFINITY;
#pragma unroll 2
    for (int g = 0; g < NN / 4; ++g) {
        float4 a = lds4[g * 3 + 0];
        float4 bq = lds4[g * 3 + 1];
        float4 c = lds4[g * 3 + 2];
        dist4_update(x, y, z, a, bq, c, m0, m1, m2, m3);
    }
    float mn = fminf(fminf(m0, m1), fminf(m2, m3));
    ws2[(size_t)b * MM + m] = mn;  // unique writer, no atomic needed
}

// Final: per-batch reduce mins -> cd_p, cd_t.
// grid = B, block = 256.
__global__ void __launch_bounds__(BLK) reduce_kernel(const unsigned int* __restrict__ ws1,
                                                     const float* __restrict__ ws2,
                                                     float* __restrict__ out) {
    const int b = blockIdx.x;
    const int tid = threadIdx.x;

    float sd1 = 0.f, sr1 = 0.f;
    for (int i = tid; i < NN; i += BLK) {
        float v = __uint_as_float(ws1[b * NN + i]);
        sd1 += v;
        sr1 += sqrtf(v);
    }
    float sd2 = 0.f, sr2 = 0.f;
    for (int i = tid; i < MM; i += BLK) {
        float v = ws2[(size_t)b * MM + i];
        sd2 += v;
        sr2 += sqrtf(v);
    }

    __shared__ float4 red[BLK];
    red[tid] = make_float4(sd1, sr1, sd2, sr2);
    __syncthreads();
    for (int s = BLK / 2; s > 0; s >>= 1) {
        if (tid < s) {
            red[tid].x += red[tid + s].x;
            red[tid].y += red[tid + s].y;
            red[tid].z += red[tid + s].z;
            red[tid].w += red[tid + s].w;
        }
        __syncthreads();
    }
    if (tid == 0) {
        float4 r = red[0];
        // cd_p = (mean(sqrt(d2_p1)) + mean(sqrt(d2_p2))) / 2
        out[b] = (r.y * (1.0f / NN) + r.w * (1.0f / MM)) * 0.5f;
        // cd_t = mean(d2_p1) + mean(d2_p2)
        out[BB + b] = r.x * (1.0f / NN) + r.z * (1.0f / MM);
    }
}

extern "C" void kernel_launch(void* const* d_in, const int* in_sizes, int n_in,
                              void* d_out, int out_size, void* d_ws, size_t ws_size,
                              hipStream_t stream) {
    const float* ref  = (const float*)d_in[0];   // [B, M, 3]
    const float* samp = (const float*)d_in[1];   // [B, N, 3]
    float* out = (float*)d_out;                  // [cd_p[16], cd_t[16]]

    unsigned int* ws1 = (unsigned int*)d_ws;                       // B*N  partial mins (bits)
    float* ws2 = (float*)((char*)d_ws + (size_t)BB * NN * sizeof(float)); // B*M mins

    init_ws<<<(BB * NN + BLK - 1) / BLK, BLK, 0, stream>>>(ws1);

    dim3 g1(BB, NN / BLK, MM / TILE_PTS);  // (16, 8, 4)
    p1_kernel<<<g1, BLK, 0, stream>>>(ref, samp, ws1);

    dim3 g2(BB, MM / BLK);                 // (16, 32)
    p2_kernel<<<g2, BLK, 0, stream>>>(ref, samp, ws2);

    reduce_kernel<<<BB, BLK, 0, stream>>>(ws1, ws2, out);
}

// Round 2
// 138.322 us; speedup vs baseline: 1.1058x; 1.1058x over previous
//
#include <hip/hip_runtime.h>
#include <math.h>

// Problem constants: B=16, N=2048 samp, M=8192 ref, fp32.
#define BB 16
#define NN 2048
#define MM 8192

#define TILE_PTS 1024            // points staged in LDS per block (float4 -> 16 KB)
#define BLK 256

// Init partial-min arrays (ws1: B*N for samp->ref, ws2: B*M for ref->samp) to +inf bits.
__global__ void init_ws(unsigned int* __restrict__ ws) {
    int i = blockIdx.x * blockDim.x + threadIdx.x;
    if (i < BB * (NN + MM)) ws[i] = 0x7F800000u;  // +inf
}

// Shared inner loop: given query (x,y,z) and an LDS tile of (p1,p2,p3,q) float4s,
// return min over tile of (q - 2*x.p). 4 VALU per point: 3 fma + 1 min.
__device__ __forceinline__ float tile_min(const float4* __restrict__ lds,
                                          float x1n, float x2n, float x3n) {
    float m0 = INFINITY, m1 = INFINITY, m2 = INFINITY, m3 = INFINITY;
#pragma unroll 2
    for (int g = 0; g < TILE_PTS / 4; ++g) {
        float4 a = lds[g * 4 + 0];
        float4 b = lds[g * 4 + 1];
        float4 c = lds[g * 4 + 2];
        float4 d = lds[g * 4 + 3];
        float t0 = fmaf(x1n, a.x, a.w); t0 = fmaf(x2n, a.y, t0); t0 = fmaf(x3n, a.z, t0);
        m0 = fminf(m0, t0);
        float t1 = fmaf(x1n, b.x, b.w); t1 = fmaf(x2n, b.y, t1); t1 = fmaf(x3n, b.z, t1);
        m1 = fminf(m1, t1);
        float t2 = fmaf(x1n, c.x, c.w); t2 = fmaf(x2n, c.y, t2); t2 = fmaf(x3n, c.z, t2);
        m2 = fminf(m2, t2);
        float t3 = fmaf(x1n, d.x, d.w); t3 = fmaf(x2n, d.y, t3); t3 = fmaf(x3n, d.z, t3);
        m3 = fminf(m3, t3);
    }
    return fminf(fminf(m0, m1), fminf(m2, m3));
}

// Stage TILE_PTS points from global [.,3] layout into LDS as (p1,p2,p3,||p||^2).
__device__ __forceinline__ void stage_tile(float4* __restrict__ lds,
                                           const float* __restrict__ src) {
    for (int i = threadIdx.x; i < TILE_PTS; i += BLK) {
        float p1 = src[i * 3 + 0], p2 = src[i * 3 + 1], p3 = src[i * 3 + 2];
        float q = fmaf(p1, p1, fmaf(p2, p2, p3 * p3));
        lds[i] = make_float4(p1, p2, p3, q);
    }
    __syncthreads();
}

// P1: each thread owns one samp point (b,n), min over a chunk of ref points.
// grid = (B, N/BLK, M/TILE_PTS) = (16, 8, 8)
__global__ void __launch_bounds__(BLK) p1_kernel(const float* __restrict__ ref,
                                                 const float* __restrict__ samp,
                                                 unsigned int* __restrict__ ws1) {
    __shared__ float4 lds[TILE_PTS];
    const int b = blockIdx.x;
    stage_tile(lds, ref + ((size_t)b * MM + (size_t)blockIdx.z * TILE_PTS) * 3);

    const int n = blockIdx.y * BLK + threadIdx.x;
    const float* sp = samp + ((size_t)b * NN + n) * 3;
    const float x1 = sp[0], x2 = sp[1], x3 = sp[2];
    const float qx = fmaf(x1, x1, fmaf(x2, x2, x3 * x3));

    float mn = tile_min(lds, -2.f * x1, -2.f * x2, -2.f * x3);
    float v = fmaxf(qx + mn, 0.f);            // >= 0 -> uint-ordered atomicMin valid
    atomicMin(&ws1[b * NN + n], __float_as_uint(v));
}

// P2: each thread owns one ref point (b,m), min over a chunk of samp points.
// grid = (B, M/BLK, N/TILE_PTS) = (16, 32, 2)
__global__ void __launch_bounds__(BLK) p2_kernel(const float* __restrict__ ref,
                                                 const float* __restrict__ samp,
                                                 unsigned int* __restrict__ ws2) {
    __shared__ float4 lds[TILE_PTS];
    const int b = blockIdx.x;
    stage_tile(lds, samp + ((size_t)b * NN + (size_t)blockIdx.z * TILE_PTS) * 3);

    const int m = blockIdx.y * BLK + threadIdx.x;
    const float* rp = ref + ((size_t)b * MM + m) * 3;
    const float x1 = rp[0], x2 = rp[1], x3 = rp[2];
    const float qx = fmaf(x1, x1, fmaf(x2, x2, x3 * x3));

    float mn = tile_min(lds, -2.f * x1, -2.f * x2, -2.f * x3);
    float v = fmaxf(qx + mn, 0.f);
    atomicMin(&ws2[(size_t)b * MM + m], __float_as_uint(v));
}

// Final: per-batch reduce mins -> cd_p, cd_t.  grid = B, block = 256.
__global__ void __launch_bounds__(BLK) reduce_kernel(const unsigned int* __restrict__ ws1,
                                                     const unsigned int* __restrict__ ws2,
                                                     float* __restrict__ out) {
    const int b = blockIdx.x;
    const int tid = threadIdx.x;

    float sd1 = 0.f, sr1 = 0.f;
    for (int i = tid; i < NN; i += BLK) {
        float v = __uint_as_float(ws1[b * NN + i]);
        sd1 += v;
        sr1 += sqrtf(v);
    }
    float sd2 = 0.f, sr2 = 0.f;
    for (int i = tid; i < MM; i += BLK) {
        float v = __uint_as_float(ws2[(size_t)b * MM + i]);
        sd2 += v;
        sr2 += sqrtf(v);
    }

    __shared__ float4 red[BLK];
    red[tid] = make_float4(sd1, sr1, sd2, sr2);
    __syncthreads();
    for (int s = BLK / 2; s > 0; s >>= 1) {
        if (tid < s) {
            red[tid].x += red[tid + s].x;
            red[tid].y += red[tid + s].y;
            red[tid].z += red[tid + s].z;
            red[tid].w += red[tid + s].w;
        }
        __syncthreads();
    }
    if (tid == 0) {
        float4 r = red[0];
        out[b]      = (r.y * (1.0f / NN) + r.w * (1.0f / MM)) * 0.5f;  // cd_p
        out[BB + b] = r.x * (1.0f / NN) + r.z * (1.0f / MM);           // cd_t
    }
}

extern "C" void kernel_launch(void* const* d_in, const int* in_sizes, int n_in,
                              void* d_out, int out_size, void* d_ws, size_t ws_size,
                              hipStream_t stream) {
    const float* ref  = (const float*)d_in[0];   // [B, M, 3]
    const float* samp = (const float*)d_in[1];   // [B, N, 3]
    float* out = (float*)d_out;                  // [cd_p[16], cd_t[16]]

    unsigned int* ws1 = (unsigned int*)d_ws;                 // B*N partial mins (bits)
    unsigned int* ws2 = ws1 + (size_t)BB * NN;               // B*M partial mins (bits)

    init_ws<<<(BB * (NN + MM) + BLK - 1) / BLK, BLK, 0, stream>>>(ws1);

    dim3 g1(BB, NN / BLK, MM / TILE_PTS);   // (16, 8, 8) = 1024 blocks
    p1_kernel<<<g1, BLK, 0, stream>>>(ref, samp, ws1);

    dim3 g2(BB, MM / BLK, NN / TILE_PTS);   // (16, 32, 2) = 1024 blocks
    p2_kernel<<<g2, BLK, 0, stream>>>(ref, samp, ws2);

    reduce_kernel<<<BB, BLK, 0, stream>>>(ws1, ws2, out);
}

// Round 3
// 126.613 us; speedup vs baseline: 1.2081x; 1.0925x over previous
//
#include <hip/hip_runtime.h>
#include <math.h>

// Problem: chamfer distance. B=16, N=2048 samp, M=8192 ref, fp32.
#define BB 16
#define NN 2048
#define MM 8192

#define BLK 256
#define Q 4            // queries per thread
#define TILE 256       // tile points per block (read via uniform/scalar loads)

// ws layout (float4-aligned):
//   ref4  : float4[BB*MM]   packed (x,y,z,||p||^2)
//   samp4 : float4[BB*NN]
//   ws1   : uint[BB*NN]     samp->ref partial mins (bits, >=0 so uint-ordered)
//   ws2   : uint[BB*MM]     ref->samp partial mins

// Pack both clouds into (x,y,z,q) float4 and init the min arrays to +inf.
__global__ void __launch_bounds__(BLK) prep_kernel(const float* __restrict__ ref,
                                                   const float* __restrict__ samp,
                                                   float4* __restrict__ ref4,
                                                   float4* __restrict__ samp4,
                                                   unsigned int* __restrict__ ws1,
                                                   unsigned int* __restrict__ ws2) {
    int i = blockIdx.x * blockDim.x + threadIdx.x;
    const int PM = BB * MM, PN = BB * NN;
    if (i < PM) {
        float p1 = ref[(size_t)i * 3 + 0], p2 = ref[(size_t)i * 3 + 1], p3 = ref[(size_t)i * 3 + 2];
        ref4[i] = make_float4(p1, p2, p3, fmaf(p1, p1, fmaf(p2, p2, p3 * p3)));
        ws2[i] = 0x7F800000u;
    } else if (i < PM + PN) {
        int k = i - PM;
        float p1 = samp[(size_t)k * 3 + 0], p2 = samp[(size_t)k * 3 + 1], p3 = samp[(size_t)k * 3 + 2];
        samp4[k] = make_float4(p1, p2, p3, fmaf(p1, p1, fmaf(p2, p2, p3 * p3)));
        ws1[k] = 0x7F800000u;
    }
}

// Core: Q queries per thread vs a TILE-point chunk read with wave-uniform
// addresses (-> s_load through the scalar cache; no LDS, no barriers).
__device__ __forceinline__ void chamfer_pass(const float4* __restrict__ qbase, int qstride_sel,
                                             const float4* __restrict__ tile,
                                             unsigned int* __restrict__ wmin,
                                             int qidx0) {
    float nx[Q], ny[Q], nz[Q], qx[Q], mn[Q];
#pragma unroll
    for (int q = 0; q < Q; ++q) {
        float4 s = qbase[qidx0 + q * BLK];
        nx[q] = -2.f * s.x; ny[q] = -2.f * s.y; nz[q] = -2.f * s.z;
        qx[q] = s.w;
        mn[q] = INFINITY;
    }

#pragma unroll 4
    for (int j = 0; j < TILE; ++j) {
        float4 r = tile[j];          // wave-uniform -> scalar load
        float qv = r.w;
#pragma unroll
        for (int q = 0; q < Q; ++q) {
            float t = fmaf(nx[q], r.x, qv);
            t = fmaf(ny[q], r.y, t);
            t = fmaf(nz[q], r.z, t);
            mn[q] = fminf(mn[q], t);
        }
    }

#pragma unroll
    for (int q = 0; q < Q; ++q) {
        float v = fmaxf(qx[q] + mn[q], 0.f);
        atomicMin(&wmin[qidx0 + q * BLK], __float_as_uint(v));
    }
    (void)qstride_sel;
}

// P1: queries = samp points, tiles = ref points.
// grid = (B, N/(BLK*Q)=2, M/TILE=32) = 1024 blocks
__global__ void __launch_bounds__(BLK) p1_kernel(const float4* __restrict__ ref4,
                                                 const float4* __restrict__ samp4,
                                                 unsigned int* __restrict__ ws1) {
    const int b = blockIdx.x;
    const int qidx0 = blockIdx.y * (BLK * Q) + threadIdx.x;
    const float4* tile = ref4 + (size_t)b * MM + (size_t)blockIdx.z * TILE;
    chamfer_pass(samp4 + (size_t)b * NN, 0, tile, ws1 + (size_t)b * NN, qidx0);
}

// P2: queries = ref points, tiles = samp points.
// grid = (B, M/(BLK*Q)=8, N/TILE=8) = 1024 blocks
__global__ void __launch_bounds__(BLK) p2_kernel(const float4* __restrict__ ref4,
                                                 const float4* __restrict__ samp4,
                                                 unsigned int* __restrict__ ws2) {
    const int b = blockIdx.x;
    const int qidx0 = blockIdx.y * (BLK * Q) + threadIdx.x;
    const float4* tile = samp4 + (size_t)b * NN + (size_t)blockIdx.z * TILE;
    chamfer_pass(ref4 + (size_t)b * MM, 0, tile, ws2 + (size_t)b * MM, qidx0);
}

// Final: per-batch reduce mins -> cd_p, cd_t.  grid = B, block = 1024.
#define BLKR 1024
__global__ void __launch_bounds__(BLKR) reduce_kernel(const unsigned int* __restrict__ ws1,
                                                      const unsigned int* __restrict__ ws2,
                                                      float* __restrict__ out) {
    const int b = blockIdx.x;
    const int tid = threadIdx.x;

    float sd1 = 0.f, sr1 = 0.f;
    for (int i = tid; i < NN; i += BLKR) {
        float v = __uint_as_float(ws1[b * NN + i]);
        sd1 += v;
        sr1 += sqrtf(v);
    }
    float sd2 = 0.f, sr2 = 0.f;
    for (int i = tid; i < MM; i += BLKR) {
        float v = __uint_as_float(ws2[(size_t)b * MM + i]);
        sd2 += v;
        sr2 += sqrtf(v);
    }

    __shared__ float4 red[BLKR];
    red[tid] = make_float4(sd1, sr1, sd2, sr2);
    __syncthreads();
    for (int s = BLKR / 2; s > 0; s >>= 1) {
        if (tid < s) {
            red[tid].x += red[tid + s].x;
            red[tid].y += red[tid + s].y;
            red[tid].z += red[tid + s].z;
            red[tid].w += red[tid + s].w;
        }
        __syncthreads();
    }
    if (tid == 0) {
        float4 r = red[0];
        out[b]      = (r.y * (1.0f / NN) + r.w * (1.0f / MM)) * 0.5f;  // cd_p
        out[BB + b] = r.x * (1.0f / NN) + r.z * (1.0f / MM);           // cd_t
    }
}

extern "C" void kernel_launch(void* const* d_in, const int* in_sizes, int n_in,
                              void* d_out, int out_size, void* d_ws, size_t ws_size,
                              hipStream_t stream) {
    const float* ref  = (const float*)d_in[0];   // [B, M, 3]
    const float* samp = (const float*)d_in[1];   // [B, N, 3]
    float* out = (float*)d_out;                  // [cd_p[16], cd_t[16]]

    float4* ref4  = (float4*)d_ws;                                   // BB*MM
    float4* samp4 = ref4 + (size_t)BB * MM;                          // BB*NN
    unsigned int* ws1 = (unsigned int*)(samp4 + (size_t)BB * NN);    // BB*NN
    unsigned int* ws2 = ws1 + (size_t)BB * NN;                       // BB*MM

    const int P = BB * (MM + NN);
    prep_kernel<<<(P + BLK - 1) / BLK, BLK, 0, stream>>>(ref, samp, ref4, samp4, ws1, ws2);

    dim3 g1(BB, NN / (BLK * Q), MM / TILE);   // (16, 2, 32) = 1024 blocks
    p1_kernel<<<g1, BLK, 0, stream>>>(ref4, samp4, ws1);

    dim3 g2(BB, MM / (BLK * Q), NN / TILE);   // (16, 8, 8) = 1024 blocks
    p2_kernel<<<g2, BLK, 0, stream>>>(ref4, samp4, ws2);

    reduce_kernel<<<BB, BLKR, 0, stream>>>(ws1, ws2, out);
}

// Round 4
// 119.430 us; speedup vs baseline: 1.2807x; 1.0601x over previous
//
#include <hip/hip_runtime.h>
#include <math.h>

// Chamfer distance, fused single-sweep. B=16, N=2048 samp, M=8192 ref, fp32.
#define BB 16
#define NN 2048
#define MM 8192

#define BLK 256
#define R 16                 // ref points resident per lane (in VGPRs)
#define NSPLIT 32            // query-stream chunks (parallelism in N)
#define QCH (NN / NSPLIT)    // 64 queries per wave

// ws layout (float4-aligned):
//   ref4  : float4[BB*MM]  (-2x, -2y, -2z, ||p||^2)   lane-resident side
//   samp4 : float4[BB*NN]  ( x,   y,   z, ||p||^2)    streamed side
//   ws1   : uint[BB*NN]    samp->ref mins (bits, >=0 so uint-ordered)
//   ws2   : uint[BB*MM]    ref->samp mins

__global__ void __launch_bounds__(BLK) prep_kernel(const float* __restrict__ ref,
                                                   const float* __restrict__ samp,
                                                   float4* __restrict__ ref4,
                                                   float4* __restrict__ samp4,
                                                   unsigned int* __restrict__ ws1,
                                                   unsigned int* __restrict__ ws2) {
    int i = blockIdx.x * blockDim.x + threadIdx.x;
    const int PM = BB * MM, PN = BB * NN;
    if (i < PM) {
        float p1 = ref[(size_t)i * 3 + 0], p2 = ref[(size_t)i * 3 + 1], p3 = ref[(size_t)i * 3 + 2];
        float q = fmaf(p1, p1, fmaf(p2, p2, p3 * p3));
        ref4[i] = make_float4(-2.f * p1, -2.f * p2, -2.f * p3, q);
        ws2[i] = 0x7F800000u;
    } else if (i < PM + PN) {
        int k = i - PM;
        float p1 = samp[(size_t)k * 3 + 0], p2 = samp[(size_t)k * 3 + 1], p3 = samp[(size_t)k * 3 + 2];
        float q = fmaf(p1, p1, fmaf(p2, p2, p3 * p3));
        samp4[k] = make_float4(p1, p2, p3, q);
        ws1[k] = 0x7F800000u;
    }
}

// Fused sweep: grid = (B, MM/(4*64*R)=2, NSPLIT=32) = 1024 blocks, 4096 waves.
// Each wave: 64*R=1024 refs resident in VGPRs, streams QCH=64 samp queries.
// Computes min in BOTH directions from one pass over the 64R x QCH distances.
__global__ void __launch_bounds__(BLK, 4) sweep_kernel(const float4* __restrict__ ref4,
                                                       const float4* __restrict__ samp4,
                                                       unsigned int* __restrict__ ws1,
                                                       unsigned int* __restrict__ ws2) {
    const int b = blockIdx.x;
    const int lane = threadIdx.x & 63;
    const int wv = threadIdx.x >> 6;                       // wave in block: 0..3
    const int refbase = (blockIdx.y * 4 + wv) * (64 * R);  // 1024 refs per wave

    const float4* rp = ref4 + (size_t)b * MM + refbase;
    float px[R], py[R], pz[R], pp[R], mref[R];
#pragma unroll
    for (int r = 0; r < R; ++r) {
        float4 v = rp[r * 64 + lane];                      // coalesced
        px[r] = v.x; py[r] = v.y; pz[r] = v.z; pp[r] = v.w;
        mref[r] = INFINITY;
    }

    const float4* qt = samp4 + (size_t)b * NN + (size_t)blockIdx.z * QCH;
    unsigned int* w1 = ws1 + (size_t)b * NN + (size_t)blockIdx.z * QCH;

    for (int j = 0; j < QCH; ++j) {
        float4 q = qt[j];                                  // broadcast load (L1-hot)
        float tq = INFINITY;
#pragma unroll
        for (int r = 0; r < R; ++r) {
            float t = fmaf(px[r], q.x, pp[r]);             // pp - 2*dot
            t = fmaf(py[r], q.y, t);
            t = fmaf(pz[r], q.z, t);
            mref[r] = fminf(mref[r], t + q.w);             // ref-direction
            tq = fminf(tq, t);                             // query-direction (q.w deferred)
        }
        // wave-wide min of tq (64 lanes)
#pragma unroll
        for (int s = 32; s > 0; s >>= 1)
            tq = fminf(tq, __shfl_xor(tq, s));
        if (lane == 0) {
            float v = fmaxf(tq + q.w, 0.f);
            atomicMin(&w1[j], __float_as_uint(v));
        }
    }

    unsigned int* w2 = ws2 + (size_t)b * MM + refbase;
#pragma unroll
    for (int r = 0; r < R; ++r) {
        float v = fmaxf(mref[r], 0.f);
        atomicMin(&w2[r * 64 + lane], __float_as_uint(v));
    }
}

// Final: per-batch reduce mins -> cd_p, cd_t.  grid = B, block = 1024.
#define BLKR 1024
__global__ void __launch_bounds__(BLKR) reduce_kernel(const unsigned int* __restrict__ ws1,
                                                      const unsigned int* __restrict__ ws2,
                                                      float* __restrict__ out) {
    const int b = blockIdx.x;
    const int tid = threadIdx.x;

    float sd1 = 0.f, sr1 = 0.f;
    for (int i = tid; i < NN; i += BLKR) {
        float v = __uint_as_float(ws1[b * NN + i]);
        sd1 += v;
        sr1 += sqrtf(v);
    }
    float sd2 = 0.f, sr2 = 0.f;
    for (int i = tid; i < MM; i += BLKR) {
        float v = __uint_as_float(ws2[(size_t)b * MM + i]);
        sd2 += v;
        sr2 += sqrtf(v);
    }

    __shared__ float4 red[BLKR];
    red[tid] = make_float4(sd1, sr1, sd2, sr2);
    __syncthreads();
    for (int s = BLKR / 2; s > 0; s >>= 1) {
        if (tid < s) {
            red[tid].x += red[tid + s].x;
            red[tid].y += red[tid + s].y;
            red[tid].z += red[tid + s].z;
            red[tid].w += red[tid + s].w;
        }
        __syncthreads();
    }
    if (tid == 0) {
        float4 r = red[0];
        out[b]      = (r.y * (1.0f / NN) + r.w * (1.0f / MM)) * 0.5f;  // cd_p
        out[BB + b] = r.x * (1.0f / NN) + r.z * (1.0f / MM);           // cd_t
    }
}

extern "C" void kernel_launch(void* const* d_in, const int* in_sizes, int n_in,
                              void* d_out, int out_size, void* d_ws, size_t ws_size,
                              hipStream_t stream) {
    const float* ref  = (const float*)d_in[0];   // [B, M, 3]
    const float* samp = (const float*)d_in[1];   // [B, N, 3]
    float* out = (float*)d_out;                  // [cd_p[16], cd_t[16]]

    float4* ref4  = (float4*)d_ws;                                   // BB*MM
    float4* samp4 = ref4 + (size_t)BB * MM;                          // BB*NN
    unsigned int* ws1 = (unsigned int*)(samp4 + (size_t)BB * NN);    // BB*NN
    unsigned int* ws2 = ws1 + (size_t)BB * NN;                       // BB*MM

    const int P = BB * (MM + NN);
    prep_kernel<<<(P + BLK - 1) / BLK, BLK, 0, stream>>>(ref, samp, ref4, samp4, ws1, ws2);

    dim3 gs(BB, MM / (4 * 64 * R), NSPLIT);   // (16, 2, 32) = 1024 blocks
    sweep_kernel<<<gs, BLK, 0, stream>>>(ref4, samp4, ws1, ws2);

    reduce_kernel<<<BB, BLKR, 0, stream>>>(ws1, ws2, out);
}

// Round 5
// 117.529 us; speedup vs baseline: 1.3014x; 1.0162x over previous
//
#include <hip/hip_runtime.h>
#include <math.h>

// Chamfer distance, fused single-sweep. B=16, N=2048 samp, M=8192 ref, fp32.
#define BB 16
#define NN 2048
#define MM 8192

#define BLK 256
#define R 8                  // ref points resident per lane (40 VGPRs) -- fits any occupancy target
#define QCH 32               // queries streamed per block
#define NSPLIT (NN / QCH)    // 64

// ws layout (float4-aligned):
//   ref4  : float4[BB*MM]  (-2x, -2y, -2z, ||p||^2)   lane-resident side
//   samp4 : float4[BB*NN]  ( x,   y,   z, ||p||^2)    streamed side
//   ws1   : uint[BB*NN]    samp->ref mins (bits, >=0 so uint-ordered)
//   ws2   : uint[BB*MM]    ref->samp mins

__global__ void __launch_bounds__(BLK) prep_kernel(const float* __restrict__ ref,
                                                   const float* __restrict__ samp,
                                                   float4* __restrict__ ref4,
                                                   float4* __restrict__ samp4,
                                                   unsigned int* __restrict__ ws1,
                                                   unsigned int* __restrict__ ws2) {
    int i = blockIdx.x * blockDim.x + threadIdx.x;
    const int PM = BB * MM, PN = BB * NN;
    if (i < PM) {
        float p1 = ref[(size_t)i * 3 + 0], p2 = ref[(size_t)i * 3 + 1], p3 = ref[(size_t)i * 3 + 2];
        float q = fmaf(p1, p1, fmaf(p2, p2, p3 * p3));
        ref4[i] = make_float4(-2.f * p1, -2.f * p2, -2.f * p3, q);
        ws2[i] = 0x7F800000u;
    } else if (i < PM + PN) {
        int k = i - PM;
        float p1 = samp[(size_t)k * 3 + 0], p2 = samp[(size_t)k * 3 + 1], p3 = samp[(size_t)k * 3 + 2];
        float q = fmaf(p1, p1, fmaf(p2, p2, p3 * p3));
        samp4[k] = make_float4(p1, p2, p3, q);
        ws1[k] = 0x7F800000u;
    }
}

// Fused sweep. grid = (B, MM/(BLK*R)=4, NSPLIT=64) = 4096 blocks.
// Block: 2048 refs resident in VGPRs (8/lane), streams QCH=32 samp queries.
// Both direction mins from one pass; query-direction partials go to LDS
// (1 ds_write/lane/query) and are reduced once at block end.
__global__ void __launch_bounds__(BLK, 5) sweep_kernel(const float4* __restrict__ ref4,
                                                       const float4* __restrict__ samp4,
                                                       unsigned int* __restrict__ ws1,
                                                       unsigned int* __restrict__ ws2) {
    __shared__ float tqbuf[QCH * BLK];                     // [j][tid], 32 KB
    const int b = blockIdx.x;
    const int lane = threadIdx.x & 63;
    const int wv = threadIdx.x >> 6;                       // wave in block: 0..3
    const int refbase = blockIdx.y * (BLK * R) + wv * (64 * R);

    const float4* rp = ref4 + (size_t)b * MM + refbase;
    float px[R], py[R], pz[R], pp[R], mref[R];
#pragma unroll
    for (int r = 0; r < R; ++r) {
        float4 v = rp[r * 64 + lane];                      // coalesced
        px[r] = v.x; py[r] = v.y; pz[r] = v.z; pp[r] = v.w;
        mref[r] = INFINITY;
    }

    const int q0 = blockIdx.z * QCH;
    const float4* qt = samp4 + (size_t)b * NN + q0;

#pragma unroll 4
    for (int j = 0; j < QCH; ++j) {
        float4 q = qt[j];                                  // uniform -> scalar/broadcast load
        float t[R];
#pragma unroll
        for (int r = 0; r < R; ++r) {
            float s = fmaf(px[r], q.x, pp[r]);             // pp - 2*dot
            s = fmaf(py[r], q.y, s);
            s = fmaf(pz[r], q.z, s);
            t[r] = s;
            mref[r] = fminf(mref[r], s + q.w);             // ref-direction
        }
        // query-direction: pairwise -> v_min3
        float tq = fminf(t[0], t[1]);
#pragma unroll
        for (int r = 2; r < R; r += 2)
            tq = fminf(tq, fminf(t[r], t[r + 1]));
        tqbuf[j * BLK + threadIdx.x] = tq;                 // conflict-free, offset-folded
    }

    // ref-direction results (registers; no barrier dependency)
    unsigned int* w2 = ws2 + (size_t)b * MM + refbase;
#pragma unroll
    for (int r = 0; r < R; ++r)
        atomicMin(&w2[r * 64 + lane], __float_as_uint(fmaxf(mref[r], 0.f)));

    __syncthreads();

    // query-direction: wave wv reduces queries j = wv*8 .. wv*8+7.
    // 256 partials per query are contiguous -> one ds_read_b128 per wave.
    unsigned int* w1 = ws1 + (size_t)b * NN + q0;
#pragma unroll
    for (int jj = 0; jj < QCH / 4; ++jj) {
        const int j = wv * (QCH / 4) + jj;
        const float4* s4 = (const float4*)(tqbuf + j * BLK);
        float4 v = s4[lane];
        float m = fminf(fminf(v.x, v.y), fminf(v.z, v.w));
#pragma unroll
        for (int s = 32; s > 0; s >>= 1)
            m = fminf(m, __shfl_xor(m, s));
        if (lane == 0) {
            float qw = qt[j].w;
            atomicMin(&w1[j], __float_as_uint(fmaxf(m + qw, 0.f)));
        }
    }
}

// Final: per-batch reduce mins -> cd_p, cd_t.  grid = B, block = 1024.
#define BLKR 1024
__global__ void __launch_bounds__(BLKR) reduce_kernel(const unsigned int* __restrict__ ws1,
                                                      const unsigned int* __restrict__ ws2,
                                                      float* __restrict__ out) {
    const int b = blockIdx.x;
    const int tid = threadIdx.x;

    float sd1 = 0.f, sr1 = 0.f;
    for (int i = tid; i < NN; i += BLKR) {
        float v = __uint_as_float(ws1[b * NN + i]);
        sd1 += v;
        sr1 += sqrtf(v);
    }
    float sd2 = 0.f, sr2 = 0.f;
    for (int i = tid; i < MM; i += BLKR) {
        float v = __uint_as_float(ws2[(size_t)b * MM + i]);
        sd2 += v;
        sr2 += sqrtf(v);
    }

    __shared__ float4 red[BLKR];
    red[tid] = make_float4(sd1, sr1, sd2, sr2);
    __syncthreads();
    for (int s = BLKR / 2; s > 0; s >>= 1) {
        if (tid < s) {
            red[tid].x += red[tid + s].x;
            red[tid].y += red[tid + s].y;
            red[tid].z += red[tid + s].z;
            red[tid].w += red[tid + s].w;
        }
        __syncthreads();
    }
    if (tid == 0) {
        float4 r = red[0];
        out[b]      = (r.y * (1.0f / NN) + r.w * (1.0f / MM)) * 0.5f;  // cd_p
        out[BB + b] = r.x * (1.0f / NN) + r.z * (1.0f / MM);           // cd_t
    }
}

extern "C" void kernel_launch(void* const* d_in, const int* in_sizes, int n_in,
                              void* d_out, int out_size, void* d_ws, size_t ws_size,
                              hipStream_t stream) {
    const float* ref  = (const float*)d_in[0];   // [B, M, 3]
    const float* samp = (const float*)d_in[1];   // [B, N, 3]
    float* out = (float*)d_out;                  // [cd_p[16], cd_t[16]]

    float4* ref4  = (float4*)d_ws;                                   // BB*MM
    float4* samp4 = ref4 + (size_t)BB * MM;                          // BB*NN
    unsigned int* ws1 = (unsigned int*)(samp4 + (size_t)BB * NN);    // BB*NN
    unsigned int* ws2 = ws1 + (size_t)BB * NN;                       // BB*MM

    const int P = BB * (MM + NN);
    prep_kernel<<<(P + BLK - 1) / BLK, BLK, 0, stream>>>(ref, samp, ref4, samp4, ws1, ws2);

    dim3 gs(BB, MM / (BLK * R), NSPLIT);   // (16, 4, 64) = 4096 blocks
    sweep_kernel<<<gs, BLK, 0, stream>>>(ref4, samp4, ws1, ws2);

    reduce_kernel<<<BB, BLKR, 0, stream>>>(ws1, ws2, out);
}